// Round 15
// baseline (234.537 us; speedup 1.0000x reference)
//
#include <hip/hip_runtime.h>
#include <math.h>

#define T 2048
#define HIDDEN 2048
#define NH 16
#define NKV 4
#define HD 128
#define QKV_N 3072   // (16 + 2*4) * 128
#define Q_SIZE 2048  // 16*128
#define KV_SIZE 512  // 4*128

typedef __attribute__((ext_vector_type(8))) short short8;
typedef __attribute__((ext_vector_type(4))) short short4v;
typedef __attribute__((ext_vector_type(4))) float floatx4;

__device__ __forceinline__ unsigned short f2bf(float f) {
    union { float f; unsigned int u; } v; v.f = f;
    unsigned int u = v.u;
    u += 0x7fffu + ((u >> 16) & 1u);   // round-to-nearest-even
    return (unsigned short)(u >> 16);
}

// async global->LDS, 16B per lane; LDS dest = wave-uniform base + lane*16 (HW adds it)
__device__ __forceinline__ void gload_lds16(const unsigned short* g, unsigned short* l) {
    __builtin_amdgcn_global_load_lds((const __attribute__((address_space(1))) unsigned int*)g,
                                     (__attribute__((address_space(3))) unsigned int*)l, 16, 0, 0);
}

// ---------------- fused prep: convert hb + transpose wqt + transpose wot + cos/sin ----------------
__global__ __launch_bounds__(256) void prep_misc(const float* __restrict__ hidden,
                                                 const float* __restrict__ w_qkv,
                                                 const float* __restrict__ w_o,
                                                 const int* __restrict__ positions,
                                                 unsigned short* __restrict__ hb,
                                                 unsigned short* __restrict__ wqt,
                                                 unsigned short* __restrict__ wot,
                                                 float* __restrict__ cosT,
                                                 float* __restrict__ sinT) {
    __shared__ float tile[32][33];
    const int b = blockIdx.x;
    const int tid = threadIdx.x;
    const int tx = tid & 31, ty = tid >> 5;

    if (b < 4096) {
        int i = (b * 256 + tid) * 4;
        float4 v = *(const float4*)(hidden + i);
        hb[i]     = f2bf(v.x);
        hb[i + 1] = f2bf(v.y);
        hb[i + 2] = f2bf(v.z);
        hb[i + 3] = f2bf(v.w);
    } else if (b < 10240) {
        int idx = b - 4096;
        int c0 = (idx % 96) * 32, r0 = (idx / 96) * 32;
#pragma unroll
        for (int i = 0; i < 4; ++i)
            tile[ty + i * 8][tx] = w_qkv[(long)(r0 + ty + i * 8) * QKV_N + c0 + tx];
        __syncthreads();
#pragma unroll
        for (int i = 0; i < 4; ++i)
            wqt[(long)(c0 + ty + i * 8) * HIDDEN + r0 + tx] = f2bf(tile[tx][ty + i * 8]);
    } else if (b < 14336) {
        int idx = b - 10240;
        int c0 = (idx % 64) * 32, r0 = (idx / 64) * 32;
#pragma unroll
        for (int i = 0; i < 4; ++i)
            tile[ty + i * 8][tx] = w_o[(long)(r0 + ty + i * 8) * HIDDEN + c0 + tx];
        __syncthreads();
#pragma unroll
        for (int i = 0; i < 4; ++i)
            wot[(long)(c0 + ty + i * 8) * HIDDEN + r0 + tx] = f2bf(tile[tx][ty + i * 8]);
    } else {
        int idx = b - 14336;
        int t = idx * 4 + (tid >> 6);
        int j = tid & 63;
        int row = (j >= 44) ? 0 : ((j & 1) ? 2 : 1);
        int pos = positions[row * T + t];
        float invf = exp2f((float)j * -0.29580571f);   // log2(500000)/64
        float ang = (float)pos * invf;
        cosT[t * 64 + j] = cosf(ang);
        sinT[t * 64 + j] = sinf(ang);
    }
}

// ---------------- qkv GEMM: 64x128 tile, BK=64, dbuf async, XOR-swizzled LDS, rope fused -------
__global__ __launch_bounds__(256) void gemm_qkv(const unsigned short* __restrict__ A,
                                                const unsigned short* __restrict__ B,
                                                const float* __restrict__ cosT,
                                                const float* __restrict__ sinT,
                                                unsigned short* __restrict__ qb,
                                                unsigned short* __restrict__ kb,
                                                unsigned short* __restrict__ vt) {
    __shared__ __align__(16) unsigned short As[2][64 * 64];    // 2 x 8 KB
    __shared__ __align__(16) unsigned short Bs[2][128 * 64];   // 2 x 16 KB
    const int K = HIDDEN;
    const int tid = threadIdx.x;
    const int wv = tid >> 6;
    const int lane = tid & 63;
    const int m = lane & 15, qd = lane >> 4;
    const unsigned short* Ab = A + (long)(blockIdx.x * 64) * K;
    const unsigned short* Bb = B + (long)(blockIdx.y * 128) * K;

    floatx4 acc[4][2];
#pragma unroll
    for (int i = 0; i < 4; ++i)
#pragma unroll
        for (int j = 0; j < 2; ++j) acc[i][j] = (floatx4){0.f, 0.f, 0.f, 0.f};

#define QKV_STAGE(buf, k0)                                                                   \
    do {                                                                                     \
        _Pragma("unroll") for (int i_ = 0; i_ < 2; ++i_) {                                   \
            int s_ = i_ * 256 + tid, r_ = s_ >> 3, c_ = (s_ & 7) ^ (r_ & 7);                 \
            gload_lds16(Ab + (long)r_ * K + (k0) + c_ * 8, &As[buf][i_ * 2048 + wv * 512]);  \
        }                                                                                    \
        _Pragma("unroll") for (int i_ = 0; i_ < 4; ++i_) {                                   \
            int s_ = i_ * 256 + tid, r_ = s_ >> 3, c_ = (s_ & 7) ^ (r_ & 7);                 \
            gload_lds16(Bb + (long)r_ * K + (k0) + c_ * 8, &Bs[buf][i_ * 2048 + wv * 512]);  \
        }                                                                                    \
    } while (0)

    QKV_STAGE(0, 0);
    int cur = 0;
    for (int k0 = 0; k0 < K; k0 += 64) {
        __syncthreads();                       // buf[cur] landed; prev readers of buf[cur^1] done
        if (k0 + 64 < K) QKV_STAGE(cur ^ 1, k0 + 64);
#pragma unroll
        for (int kk = 0; kk < 2; ++kk) {
            const int rch = ((kk * 4 + qd) ^ (m & 7)) * 8;
            short8 a[4], b[2];
#pragma unroll
            for (int i = 0; i < 4; ++i) a[i] = *(const short8*)&As[cur][(i * 16 + m) * 64 + rch];
#pragma unroll
            for (int j = 0; j < 2; ++j) b[j] = *(const short8*)&Bs[cur][(wv * 32 + j * 16 + m) * 64 + rch];
#pragma unroll
            for (int i = 0; i < 4; ++i)
#pragma unroll
                for (int j = 0; j < 2; ++j)
                    acc[i][j] = __builtin_amdgcn_mfma_f32_16x16x32_bf16(a[i], b[j], acc[i][j], 0, 0, 0);
        }
        cur ^= 1;
    }
#undef QKV_STAGE

    const int by = blockIdx.y;
    if (by < 20) {
        // rope path (q: by<16, k: 16..19); pairs are adjacent cols -> shfl_xor(val,1)
        const float sgn = (m & 1) ? 1.f : -1.f;
        const float qscale = 0.08838834764831845f;   // 1/sqrt(128)
#pragma unroll
        for (int i = 0; i < 4; ++i) {
#pragma unroll
            for (int r = 0; r < 4; ++r) {
                const int t = blockIdx.x * 64 + i * 16 + qd * 4 + r;
                const float* ct = cosT + t * 64;
                const float* st = sinT + t * 64;
#pragma unroll
                for (int j = 0; j < 2; ++j) {
                    const int cq = wv * 32 + j * 16 + m;
                    const int j2 = cq >> 1;
                    float val = acc[i][j][r];
                    float prt = __shfl_xor(val, 1);
                    float o = val * ct[j2] + sgn * prt * st[j2];
                    const int col = by * 128 + cq;
                    if (by < 16) qb[(long)t * Q_SIZE + col] = f2bf(o * qscale);
                    else         kb[(long)t * KV_SIZE + (col - 2048)] = f2bf(o);
                }
            }
        }
    } else {
        // v path: write V^T directly: vt[g][d][t]
        const int g = by - 20;
#pragma unroll
        for (int i = 0; i < 4; ++i)
#pragma unroll
            for (int j = 0; j < 2; ++j) {
                const int d = wv * 32 + j * 16 + m;
                const int t0 = blockIdx.x * 64 + i * 16 + qd * 4;
                unsigned short o4[4];
#pragma unroll
                for (int r = 0; r < 4; ++r) o4[r] = f2bf(acc[i][j][r]);
                *(short4v*)&vt[((long)g * HD + d) * T + t0] = *(short4v*)o4;
            }
    }
}

// ---------------- out GEMM: 64x128 tile, BK=64, dbuf async, XOR-swizzled: C(fp32) = A * B^T ----
__global__ __launch_bounds__(256) void gemm_out(const unsigned short* __restrict__ A,
                                                const unsigned short* __restrict__ B,
                                                float* __restrict__ C,
                                                int K, int ldc) {
    __shared__ __align__(16) unsigned short As[2][64 * 64];
    __shared__ __align__(16) unsigned short Bs[2][128 * 64];
    const int tid = threadIdx.x;
    const int wv = tid >> 6;
    const int lane = tid & 63;
    const int m = lane & 15, qd = lane >> 4;
    const unsigned short* Ab = A + (long)(blockIdx.x * 64) * K;
    const unsigned short* Bb = B + (long)(blockIdx.y * 128) * K;

    floatx4 acc[4][2];
#pragma unroll
    for (int i = 0; i < 4; ++i)
#pragma unroll
        for (int j = 0; j < 2; ++j) acc[i][j] = (floatx4){0.f, 0.f, 0.f, 0.f};

#define OUT_STAGE(buf, k0)                                                                   \
    do {                                                                                     \
        _Pragma("unroll") for (int i_ = 0; i_ < 2; ++i_) {                                   \
            int s_ = i_ * 256 + tid, r_ = s_ >> 3, c_ = (s_ & 7) ^ (r_ & 7);                 \
            gload_lds16(Ab + (long)r_ * K + (k0) + c_ * 8, &As[buf][i_ * 2048 + wv * 512]);  \
        }                                                                                    \
        _Pragma("unroll") for (int i_ = 0; i_ < 4; ++i_) {                                   \
            int s_ = i_ * 256 + tid, r_ = s_ >> 3, c_ = (s_ & 7) ^ (r_ & 7);                 \
            gload_lds16(Bb + (long)r_ * K + (k0) + c_ * 8, &Bs[buf][i_ * 2048 + wv * 512]);  \
        }                                                                                    \
    } while (0)

    OUT_STAGE(0, 0);
    int cur = 0;
    for (int k0 = 0; k0 < K; k0 += 64) {
        __syncthreads();
        if (k0 + 64 < K) OUT_STAGE(cur ^ 1, k0 + 64);
#pragma unroll
        for (int kk = 0; kk < 2; ++kk) {
            const int rch = ((kk * 4 + qd) ^ (m & 7)) * 8;
            short8 a[4], b[2];
#pragma unroll
            for (int i = 0; i < 4; ++i) a[i] = *(const short8*)&As[cur][(i * 16 + m) * 64 + rch];
#pragma unroll
            for (int j = 0; j < 2; ++j) b[j] = *(const short8*)&Bs[cur][(wv * 32 + j * 16 + m) * 64 + rch];
#pragma unroll
            for (int i = 0; i < 4; ++i)
#pragma unroll
                for (int j = 0; j < 2; ++j)
                    acc[i][j] = __builtin_amdgcn_mfma_f32_16x16x32_bf16(a[i], b[j], acc[i][j], 0, 0, 0);
        }
        cur ^= 1;
    }
#undef OUT_STAGE

#pragma unroll
    for (int i = 0; i < 4; ++i)
#pragma unroll
        for (int j = 0; j < 2; ++j)
#pragma unroll
            for (int r = 0; r < 4; ++r)
                C[(long)(blockIdx.x * 64 + i * 16 + qd * 4 + r) * ldc +
                  blockIdx.y * 128 + wv * 32 + j * 16 + m] = acc[i][j][r];
}

// ---------------- flash attention v10: 512-thread blocks, both K-halves in-block, fused combine -
// grid(256): bx = h*16 + c16. Waves 0-3 = half 0, waves 4-7 = half 1 (hg = tid>>8).
// Seg 0: qt=c16; seg 1: qt=15-c16 -> every block runs (qt+1)+(16-qt) = 17 aligned tile-iters
// per half-group (both halves of one qt have exactly qt+1 iters -> block barriers stay aligned).
// After each seg: half 1 writes unnormalized O + (m,l) to LDS (aliasing the K/V buffers,
// stride-65 floats), half 0 combines and writes normalized bf16 ab. No Opart / combine kernel.
#define KBUF(hg, buf) ((((hg) * 2 + (buf)) * 8192))
#define VBUF(hg) (32768 + (hg) * 8192)
#define PLS(hg, wv) (49152 + ((hg) * 4 + (wv)) * 2304)

__global__ __launch_bounds__(512, 2) void flash_attn(const unsigned short* __restrict__ qb,
                                                     const unsigned short* __restrict__ kb,
                                                     const unsigned short* __restrict__ vt,
                                                     unsigned short* __restrict__ ab) {
    __shared__ __align__(16) unsigned short smem[67584];   // 132 KB: K 64K | V 32K | P 36K
    float* Ols = (float*)smem;                             // combine staging (aliases K/V region)
    float* MLs = (float*)smem + 17000;                     // 128 float2 at ~68 KB (within K/V)

    const int tid512 = threadIdx.x;
    const int hg = tid512 >> 8;        // half-group 0/1
    const int tid = tid512 & 255;
    const int wv = tid >> 6;
    const int lane = tid & 63;
    const int m = lane & 15;
    const int qd = lane >> 4;

    const int h = blockIdx.x >> 4;
    const int c16 = blockIdx.x & 15;
    const int g = h >> 2;
    const int half = hg;
    unsigned short* myP = &smem[PLS(hg, wv)];

    for (int seg = 0; seg < 2; ++seg) {
        const int qt = seg ? (15 - c16) : c16;
        const int n0 = qt + 1;
        const int jt0 = half ? n0 : 0;
        const int jt1 = half ? 2 * qt + 2 : n0;   // both halves: qt+1 iters
        const int q0 = qt * 128;

        short8 aq[2][4];
#pragma unroll
        for (int s = 0; s < 2; ++s)
#pragma unroll
            for (int kk = 0; kk < 4; ++kk)
                aq[s][kk] = *(const short8*)(qb + (long)(q0 + s * 64 + wv * 16 + m) * Q_SIZE +
                                             h * HD + kk * 32 + qd * 8);

        floatx4 acc_o[2][8];
#pragma unroll
        for (int s = 0; s < 2; ++s)
#pragma unroll
            for (int nb = 0; nb < 8; ++nb) acc_o[s][nb] = (floatx4){0.f, 0.f, 0.f, 0.f};
        float mrow[2] = {-1e30f, -1e30f};
        float lrow[2] = {0.f, 0.f};

        // stage first K tile (XOR chunk swizzle c^(r&15))
#pragma unroll
        for (int i = 0; i < 4; ++i) {
            int s_ = i * 256 + tid;
            int r = s_ >> 4, c = (s_ & 15) ^ (r & 15);
            gload_lds16(kb + (long)(jt0 * 64 + r) * KV_SIZE + g * HD + c * 8,
                        &smem[KBUF(hg, 0) + i * 2048 + wv * 512]);
        }
        int cur = 0;
        for (int jt = jt0; jt < jt1; ++jt) {
            __syncthreads();   // K[cur] landed; all prior LDS readers done

            if (jt + 1 < jt1) {   // K prefetch -> other buffer (full iter to land)
#pragma unroll
                for (int i = 0; i < 4; ++i) {
                    int s_ = i * 256 + tid;
                    int r = s_ >> 4, c = (s_ & 15) ^ (r & 15);
                    gload_lds16(kb + (long)((jt + 1) * 64 + r) * KV_SIZE + g * HD + c * 8,
                                &smem[KBUF(hg, cur ^ 1) + i * 2048 + wv * 512]);
                }
            }
            // V for CURRENT tile (single buffer; consumed after mid barrier)
#pragma unroll
            for (int i = 0; i < 4; ++i) {
                int s_ = i * 256 + tid;
                int r = s_ >> 3, c = (s_ & 7) ^ (r & 7);
                gload_lds16(vt + ((long)g * HD + r) * T + jt * 64 + c * 8,
                            &smem[VBUF(hg) + i * 2048 + wv * 512]);
            }

            // S^T = K Q^T for both q-sets, sharing K fragment loads
            floatx4 acc_s[2][4];
#pragma unroll
            for (int s = 0; s < 2; ++s)
#pragma unroll
                for (int c = 0; c < 4; ++c) acc_s[s][c] = (floatx4){0.f, 0.f, 0.f, 0.f};
#pragma unroll
            for (int kk = 0; kk < 4; ++kk) {
#pragma unroll
                for (int c = 0; c < 4; ++c) {
                    short8 ak = *(const short8*)&smem[KBUF(hg, cur) + (c * 16 + m) * 128 +
                                                      (((4 * kk + qd) ^ m) * 8)];
                    acc_s[0][c] = __builtin_amdgcn_mfma_f32_16x16x32_bf16(ak, aq[0][kk], acc_s[0][c], 0, 0, 0);
                    acc_s[1][c] = __builtin_amdgcn_mfma_f32_16x16x32_bf16(ak, aq[1][kk], acc_s[1][c], 0, 0, 0);
                }
            }

            // per-set online softmax + P write
#pragma unroll
            for (int s = 0; s < 2; ++s) {
                const int dg = 2 * qt + s;
                if (jt >= dg) {
                    const bool full = (jt > dg);
#pragma unroll
                    for (int c = 0; c < 4; ++c)
#pragma unroll
                        for (int r = 0; r < 4; ++r)
                            if (full || (c * 16 + qd * 4 + r > wv * 16 + m)) acc_s[s][c][r] = -1e30f;
                }
                float mx = acc_s[s][0][0];
#pragma unroll
                for (int c = 0; c < 4; ++c)
#pragma unroll
                    for (int r = 0; r < 4; ++r) mx = fmaxf(mx, acc_s[s][c][r]);
                mx = fmaxf(mx, __shfl_xor(mx, 16));
                mx = fmaxf(mx, __shfl_xor(mx, 32));
                float mnew = fmaxf(mrow[s], mx);
                float alpha = __expf(mrow[s] - mnew);
                mrow[s] = mnew;

                float pv[4][4];
                float lsum = 0.f;
#pragma unroll
                for (int c = 0; c < 4; ++c)
#pragma unroll
                    for (int r = 0; r < 4; ++r) {
                        pv[c][r] = __expf(acc_s[s][c][r] - mnew);
                        lsum += pv[c][r];
                    }
                lsum += __shfl_xor(lsum, 16);
                lsum += __shfl_xor(lsum, 32);
                lrow[s] = lrow[s] * alpha + lsum;
#pragma unroll
                for (int nb = 0; nb < 8; ++nb)
#pragma unroll
                    for (int r = 0; r < 4; ++r) acc_o[s][nb][r] *= alpha;
#pragma unroll
                for (int c = 0; c < 4; ++c) {
                    short4v pk = {(short)f2bf(pv[c][0]), (short)f2bf(pv[c][1]),
                                  (short)f2bf(pv[c][2]), (short)f2bf(pv[c][3])};
                    *(short4v*)&myP[(s * 16 + m) * 72 + c * 16 + qd * 4] = pk;
                }
            }

            __syncthreads();   // V landed (and block-wide sync)

            // PV for both sets, sharing V fragment loads
#pragma unroll
            for (int kk = 0; kk < 2; ++kk) {
                short8 pa0 = *(const short8*)&myP[m * 72 + kk * 32 + qd * 8];
                short8 pa1 = *(const short8*)&myP[(16 + m) * 72 + kk * 32 + qd * 8];
#pragma unroll
                for (int nb = 0; nb < 8; ++nb) {
                    short8 av = *(const short8*)&smem[VBUF(hg) + (nb * 16 + m) * 64 +
                                                      (((4 * kk + qd) ^ (m & 7)) * 8)];
                    acc_o[0][nb] = __builtin_amdgcn_mfma_f32_16x16x32_bf16(av, pa0, acc_o[0][nb], 0, 0, 0);
                    acc_o[1][nb] = __builtin_amdgcn_mfma_f32_16x16x32_bf16(av, pa1, acc_o[1][nb], 0, 0, 0);
                }
            }
            cur ^= 1;
        }

        __syncthreads();   // loop done for both halves; safe to overwrite K/V region

        if (hg == 1) {     // half 1: stage unnormalized O + (m,l) into LDS
#pragma unroll
            for (int s = 0; s < 2; ++s) {
#pragma unroll
                for (int nb = 0; nb < 8; ++nb)
                    *(floatx4*)&Ols[tid * 65 + s * 32 + nb * 4] = acc_o[s][nb];
                if (qd == 0) {
                    MLs[(s * 64 + wv * 16 + m) * 2]     = mrow[s];
                    MLs[(s * 64 + wv * 16 + m) * 2 + 1] = lrow[s];
                }
            }
        }
        __syncthreads();

        if (hg == 0) {     // half 0: combine and write normalized bf16
#pragma unroll
            for (int s = 0; s < 2; ++s) {
                const float m1 = MLs[(s * 64 + wv * 16 + m) * 2];
                const float l1 = MLs[(s * 64 + wv * 16 + m) * 2 + 1];
                const float M = fmaxf(mrow[s], m1);
                const float a0 = __expf(mrow[s] - M);
                const float a1 = __expf(m1 - M);
                const float inv = 1.f / (lrow[s] * a0 + l1 * a1);
                const long trow = q0 + s * 64 + wv * 16 + m;
#pragma unroll
                for (int nb = 0; nb < 8; ++nb) {
                    floatx4 o1 = *(const floatx4*)&Ols[tid * 65 + s * 32 + nb * 4];
                    unsigned short o4[4];
#pragma unroll
                    for (int r = 0; r < 4; ++r)
                        o4[r] = f2bf((acc_o[s][nb][r] * a0 + o1[r] * a1) * inv);
                    *(short4v*)&ab[trow * Q_SIZE + h * HD + nb * 16 + qd * 4] = *(short4v*)o4;
                }
            }
        }
        __syncthreads();   // combine reads done before next seg overwrites K/V region
    }
}

extern "C" void kernel_launch(void* const* d_in, const int* in_sizes, int n_in,
                              void* d_out, int out_size, void* d_ws, size_t ws_size,
                              hipStream_t stream) {
    const int* positions = (const int*)d_in[0];
    const float* hidden  = (const float*)d_in[1];
    const float* w_qkv   = (const float*)d_in[2];
    const float* w_o     = (const float*)d_in[3];
    float* out = (float*)d_out;

    char* p = (char*)d_ws;
    auto alloc = [&](size_t bytes) { char* r = p; p += (bytes + 255) & ~(size_t)255; return r; };
    float* cosT = (float*)alloc((size_t)T * 64 * 4);
    float* sinT = (float*)alloc((size_t)T * 64 * 4);
    unsigned short* hb  = (unsigned short*)alloc((size_t)T * HIDDEN * 2);
    unsigned short* wqt = (unsigned short*)alloc((size_t)QKV_N * HIDDEN * 2);
    unsigned short* wot = (unsigned short*)alloc((size_t)HIDDEN * HIDDEN * 2);
    unsigned short* qb  = (unsigned short*)alloc((size_t)T * Q_SIZE * 2);
    unsigned short* kb  = (unsigned short*)alloc((size_t)T * KV_SIZE * 2);
    unsigned short* vt  = (unsigned short*)alloc((size_t)T * KV_SIZE * 2);
    unsigned short* ab  = (unsigned short*)alloc((size_t)T * Q_SIZE * 2);

    // 1) fused prep (convert + 2 transposes + cos/sin tables)
    prep_misc<<<dim3(14848), 256, 0, stream>>>(hidden, w_qkv, w_o, positions,
                                               hb, wqt, wot, cosT, sinT);
    // 2) fused qkv projection + rope -> qb (scaled), kb, vt (BK=64)
    gemm_qkv<<<dim3(T / 64, QKV_N / 128), 256, 0, stream>>>(hb, wqt, cosT, sinT, qb, kb, vt);
    // 3) fused causal attention + in-block K-split combine -> ab (512-thread blocks)
    flash_attn<<<dim3(256), 512, 0, stream>>>(qb, kb, vt, ab);
    // 4) out = attn @ w_o (BK=64)
    gemm_out<<<dim3(T / 64, HIDDEN / 128), 256, 0, stream>>>(ab, wot, out, Q_SIZE, HIDDEN);
}